// Round 3
// baseline (459.047 us; speedup 1.0000x reference)
//
#include <hip/hip_runtime.h>
#include <hip/hip_cooperative_groups.h>
#include <math.h>

namespace cg = cooperative_groups;

#define BB 16
#define CC 256
#define HH 96
#define WW 96
#define TS 104   // LDS tile row stride (floats): 96 data + halo, keeps float4 alignment

typedef float floatx4 __attribute__((ext_vector_type(4)));  // native vec for nontemporal store

// =====================================================================
// Fused cooperative kernel: pool -> grid.sync -> proj -> grid.sync -> dwconv
// Phase bodies are identical to the verified 3-kernel version (R2, 315 us).
// =====================================================================
__global__ __launch_bounds__(256) void fused_kernel(
    const float* __restrict__ x,
    const float* __restrict__ w_k, const float* __restrict__ b_k,
    const float* __restrict__ w1, const float* __restrict__ b1,
    const float* __restrict__ bn_g, const float* __restrict__ bn_b,
    const float* __restrict__ bn_m, const float* __restrict__ bn_v,
    const float* __restrict__ w2, const float* __restrict__ b2,
    float* __restrict__ pooled, float* __restrict__ weight,
    float* __restrict__ bias, float* __restrict__ out) {

    __shared__ __align__(16) float tile[50 * TS];   // dwconv half-plane tile (20.8 KB)
    __shared__ __align__(16) float t[CC];           // proj input vector
    __shared__ __align__(16) float hbuf[64];        // proj hidden (post-GELU)
    __shared__ float hpart[256];                    // proj partial dots
    __shared__ float red[9][4];                     // pool per-wave partials

    const int tid  = threadIdx.x;
    const int lane = tid & 63;
    const int wv   = tid >> 6;
    cg::grid_group grid = cg::this_grid();

    // ---------------- Phase A: 32x32 block-average pool -> pooled (B,C,3,3) --
    {
        const int r_in = tid >> 3;   // 0..31 row inside a 32x32 block
        const int c4   = tid & 7;    // 0..7  float4 inside the 32-wide block
        for (int bc = blockIdx.x; bc < BB * CC; bc += gridDim.x) {
            const float4* p4 = (const float4*)(x + (size_t)bc * (HH * WW));
            float s[9];
            #pragma unroll
            for (int bi = 0; bi < 3; ++bi)
                #pragma unroll
                for (int bj = 0; bj < 3; ++bj) {
                    float4 v = p4[(bi * 32 + r_in) * 24 + bj * 8 + c4];
                    s[bi * 3 + bj] = v.x + v.y + v.z + v.w;
                }
            #pragma unroll
            for (int k = 0; k < 9; ++k) {
                float tv = s[k];
                #pragma unroll
                for (int off = 32; off; off >>= 1) tv += __shfl_down(tv, off, 64);
                if (lane == 0) red[k][wv] = tv;
            }
            __syncthreads();
            if (tid < 9)
                pooled[bc * 9 + tid] =
                    (red[tid][0] + red[tid][1] + red[tid][2] + red[tid][3]) * (1.0f / 1024.0f);
            __syncthreads();   // protect red[] reuse on next grid-stride iter
        }
    }
    __threadfence();
    grid.sync();

    // ---------------- Phase B: MLP + softmax(G) + mix -> weight, bias --------
    for (int u = blockIdx.x; u < BB * 10; u += gridDim.x) {
        const int b = u / 10;
        const int p = u % 10;   // 0..8 = pooled pixel, 9 = global mean

        if (p < 9) {
            t[tid] = pooled[(b * CC + tid) * 9 + p];
        } else {
            float s = 0.f;
            #pragma unroll
            for (int q = 0; q < 9; ++q) s += pooled[(b * CC + tid) * 9 + q];
            t[tid] = s * (1.0f / 9.0f);
        }
        __syncthreads();

        const int o = tid & 63, part = tid >> 6;
        {
            const float4* w1r = (const float4*)(w1 + o * CC + part * 64);
            const float4* tp  = (const float4*)(t + part * 64);
            float acc = 0.f;
            #pragma unroll
            for (int k = 0; k < 16; ++k) {
                float4 a = w1r[k], v = tp[k];
                acc += a.x * v.x + a.y * v.y + a.z * v.z + a.w * v.w;
            }
            hpart[tid] = acc;
        }
        __syncthreads();
        if (tid < 64) {
            float hsum = hpart[tid] + hpart[tid + 64] + hpart[tid + 128] +
                         hpart[tid + 192] + b1[tid];
            float hn = (hsum - bn_m[tid]) * (bn_g[tid] * rsqrtf(bn_v[tid] + 1e-5f)) + bn_b[tid];
            hbuf[tid] = 0.5f * hn * (1.0f + erff(hn * 0.70710678118654752f));
        }
        __syncthreads();

        float vals[4];
        #pragma unroll
        for (int q = 0; q < 4; ++q) {
            const int j = q * 256 + tid;
            const float4* w2r = (const float4*)(w2 + j * 64);
            const float4* hb  = (const float4*)hbuf;
            float a = b2[j];
            #pragma unroll
            for (int k = 0; k < 16; ++k) {
                float4 wvv = w2r[k], hv = hb[k];
                a += wvv.x * hv.x + wvv.y * hv.y + wvv.z * hv.z + wvv.w * hv.w;
            }
            vals[q] = a;
        }
        float m = fmaxf(fmaxf(vals[0], vals[1]), fmaxf(vals[2], vals[3]));
        float e[4], sum = 0.f;
        #pragma unroll
        for (int q = 0; q < 4; ++q) { e[q] = expf(vals[q] - m); sum += e[q]; }
        const float rinv = 1.0f / sum;

        if (p < 9) {
            float ws = 0.f;
            #pragma unroll
            for (int q = 0; q < 4; ++q)
                ws += (e[q] * rinv) * w_k[(q * CC + tid) * 9 + p];
            weight[(b * CC + tid) * 9 + p] = ws;
        } else {
            float bs = 0.f;
            #pragma unroll
            for (int q = 0; q < 4; ++q)
                bs += (e[q] * rinv) * b_k[q * CC + tid];
            bias[b * CC + tid] = bs;
        }
        __syncthreads();   // protect t/hpart/hbuf reuse on next grid-stride iter
    }
    __threadfence();
    grid.sync();

    // ---------------- Phase C: dynamic depthwise 3x3 conv (SAME) + bias ------
    for (int hp = blockIdx.x; hp < BB * CC * 2; hp += gridDim.x) {
        __syncthreads();   // protect tile reuse across grid-stride iters
        const int bc   = hp >> 1;
        const int half = hp & 1;
        const int r0   = half * 48;
        const float* plane = x + (size_t)bc * (HH * WW);
        float* oplane = out + (size_t)bc * (HH * WW);

        if (tid < 50) {
            tile[tid * TS + 3]   = 0.f;      // left halo col  (c = -1)
            tile[tid * TS + 100] = 0.f;      // right halo col (c = 96)
        }
        if (tid < 98)
            tile[(half ? 49 * TS : 0) + 3 + tid] = 0.f;  // top/bottom halo row

        float wgt[9];
        #pragma unroll
        for (int k = 0; k < 9; ++k) wgt[k] = weight[bc * 9 + k];
        const float bs = bias[bc];

        {
            const int gstart = half ? 47 : 0;
            const int trow0  = half ? 0 : 1;
            const float4* p4 = (const float4*)plane + gstart * 24;
            float4* t4 = (float4*)tile + trow0 * (TS / 4);
            #pragma unroll
            for (int i = 0; i < 5; ++i) {
                const int idx4 = tid + 256 * i;          // 0..1175 (49 rows * 24 f4)
                if (idx4 < 1176) {
                    const int r  = idx4 / 24;
                    const int c4 = idx4 - r * 24;
                    t4[r * (TS / 4) + 1 + c4] = p4[r * 24 + c4];
                }
            }
        }
        __syncthreads();

        #pragma unroll
        for (int j = 0; j < 2; ++j) {
            const int pidx = tid + 256 * j;
            if (pidx < 288) {
                const int pr = pidx / 24;
                const int pc = pidx - pr * 24;
                const int h0 = pr * 4;
                const int cb = 4 + pc * 4;

                float4 m[6]; float L[6], R[6];
                #pragma unroll
                for (int r = 0; r < 6; ++r) {
                    const int a = (h0 + r) * TS + cb;
                    m[r] = *(const float4*)(tile + a);
                    L[r] = tile[a - 1];
                    R[r] = tile[a + 4];
                }
                #pragma unroll
                for (int orow = 0; orow < 4; ++orow) {
                    floatx4 acc = {bs, bs, bs, bs};
                    #pragma unroll
                    for (int r = 0; r < 3; ++r) {
                        const int rr = orow + r;
                        const float wl = wgt[r * 3 + 0], wc = wgt[r * 3 + 1],
                                    wr = wgt[r * 3 + 2];
                        acc.x += wl * L[rr]   + wc * m[rr].x + wr * m[rr].y;
                        acc.y += wl * m[rr].x + wc * m[rr].y + wr * m[rr].z;
                        acc.z += wl * m[rr].y + wc * m[rr].z + wr * m[rr].w;
                        acc.w += wl * m[rr].z + wc * m[rr].w + wr * R[rr];
                    }
                    __builtin_nontemporal_store(
                        acc, (floatx4*)(oplane + (r0 + h0 + orow) * 96 + (cb - 4)));
                }
            }
        }
    }
}

// =====================================================================
// Fallback: the verified 3-kernel pipeline (R2: 315 us), used only if the
// cooperative launch is unavailable.
// =====================================================================
__global__ __launch_bounds__(256) void pool_kernel(const float* __restrict__ x,
                                                   float* __restrict__ pooled) {
    const int bc = blockIdx.x;
    const float4* p4 = (const float4*)(x + (size_t)bc * (HH * WW));
    const int tid  = threadIdx.x;
    const int lane = tid & 63;
    const int wv   = tid >> 6;
    const int r_in = tid >> 3;
    const int c4   = tid & 7;
    __shared__ float red[9][4];

    float s[9];
    #pragma unroll
    for (int bi = 0; bi < 3; ++bi)
        #pragma unroll
        for (int bj = 0; bj < 3; ++bj) {
            float4 v = p4[(bi * 32 + r_in) * 24 + bj * 8 + c4];
            s[bi * 3 + bj] = v.x + v.y + v.z + v.w;
        }
    #pragma unroll
    for (int k = 0; k < 9; ++k) {
        float tv = s[k];
        #pragma unroll
        for (int off = 32; off; off >>= 1) tv += __shfl_down(tv, off, 64);
        if (lane == 0) red[k][wv] = tv;
    }
    __syncthreads();
    if (tid < 9)
        pooled[bc * 9 + tid] =
            (red[tid][0] + red[tid][1] + red[tid][2] + red[tid][3]) * (1.0f / 1024.0f);
}

__global__ __launch_bounds__(256) void proj_kernel(
    const float* __restrict__ pooled,
    const float* __restrict__ w1, const float* __restrict__ b1,
    const float* __restrict__ bn_g, const float* __restrict__ bn_b,
    const float* __restrict__ bn_m, const float* __restrict__ bn_v,
    const float* __restrict__ w2, const float* __restrict__ b2,
    const float* __restrict__ w_k, const float* __restrict__ b_k,
    float* __restrict__ weight, float* __restrict__ bias) {
    const int b = blockIdx.x / 10;
    const int p = blockIdx.x % 10;
    const int tid = threadIdx.x;

    __shared__ __align__(16) float t[CC];
    __shared__ __align__(16) float hbuf[64];
    __shared__ float hpart[256];

    if (p < 9) {
        t[tid] = pooled[(b * CC + tid) * 9 + p];
    } else {
        float s = 0.f;
        #pragma unroll
        for (int q = 0; q < 9; ++q) s += pooled[(b * CC + tid) * 9 + q];
        t[tid] = s * (1.0f / 9.0f);
    }
    __syncthreads();
    const int o = tid & 63, part = tid >> 6;
    {
        const float4* w1r = (const float4*)(w1 + o * CC + part * 64);
        const float4* tp  = (const float4*)(t + part * 64);
        float acc = 0.f;
        #pragma unroll
        for (int k = 0; k < 16; ++k) {
            float4 a = w1r[k], v = tp[k];
            acc += a.x * v.x + a.y * v.y + a.z * v.z + a.w * v.w;
        }
        hpart[tid] = acc;
    }
    __syncthreads();
    if (tid < 64) {
        float hsum = hpart[tid] + hpart[tid + 64] + hpart[tid + 128] +
                     hpart[tid + 192] + b1[tid];
        float hn = (hsum - bn_m[tid]) * (bn_g[tid] * rsqrtf(bn_v[tid] + 1e-5f)) + bn_b[tid];
        hbuf[tid] = 0.5f * hn * (1.0f + erff(hn * 0.70710678118654752f));
    }
    __syncthreads();
    float vals[4];
    #pragma unroll
    for (int q = 0; q < 4; ++q) {
        const int j = q * 256 + tid;
        const float4* w2r = (const float4*)(w2 + j * 64);
        const float4* hb  = (const float4*)hbuf;
        float a = b2[j];
        #pragma unroll
        for (int k = 0; k < 16; ++k) {
            float4 wvv = w2r[k], hv = hb[k];
            a += wvv.x * hv.x + wvv.y * hv.y + wvv.z * hv.z + wvv.w * hv.w;
        }
        vals[q] = a;
    }
    float m = fmaxf(fmaxf(vals[0], vals[1]), fmaxf(vals[2], vals[3]));
    float e[4], sum = 0.f;
    #pragma unroll
    for (int q = 0; q < 4; ++q) { e[q] = expf(vals[q] - m); sum += e[q]; }
    const float rinv = 1.0f / sum;
    if (p < 9) {
        float ws = 0.f;
        #pragma unroll
        for (int q = 0; q < 4; ++q)
            ws += (e[q] * rinv) * w_k[(q * CC + tid) * 9 + p];
        weight[(b * CC + tid) * 9 + p] = ws;
    } else {
        float bs = 0.f;
        #pragma unroll
        for (int q = 0; q < 4; ++q)
            bs += (e[q] * rinv) * b_k[q * CC + tid];
        bias[b * CC + tid] = bs;
    }
}

__global__ __launch_bounds__(256) void dwconv_kernel(
    const float* __restrict__ x, const float* __restrict__ weight,
    const float* __restrict__ bias, float* __restrict__ out) {
    const int bc   = blockIdx.x >> 1;
    const int half = blockIdx.x & 1;
    const int r0   = half * 48;
    const float* plane = x + (size_t)bc * (HH * WW);
    float* oplane = out + (size_t)bc * (HH * WW);
    __shared__ __align__(16) float tile[50 * TS];
    const int tid = threadIdx.x;

    if (tid < 50) {
        tile[tid * TS + 3]   = 0.f;
        tile[tid * TS + 100] = 0.f;
    }
    if (tid < 98)
        tile[(half ? 49 * TS : 0) + 3 + tid] = 0.f;

    float wgt[9];
    #pragma unroll
    for (int k = 0; k < 9; ++k) wgt[k] = weight[bc * 9 + k];
    const float bs = bias[bc];

    {
        const int gstart = half ? 47 : 0;
        const int trow0  = half ? 0 : 1;
        const float4* p4 = (const float4*)plane + gstart * 24;
        float4* t4 = (float4*)tile + trow0 * (TS / 4);
        #pragma unroll
        for (int i = 0; i < 5; ++i) {
            const int idx4 = tid + 256 * i;
            if (idx4 < 1176) {
                const int r  = idx4 / 24;
                const int c4 = idx4 - r * 24;
                t4[r * (TS / 4) + 1 + c4] = p4[r * 24 + c4];
            }
        }
    }
    __syncthreads();

    #pragma unroll
    for (int j = 0; j < 2; ++j) {
        const int pidx = tid + 256 * j;
        if (pidx < 288) {
            const int pr = pidx / 24;
            const int pc = pidx - pr * 24;
            const int h0 = pr * 4;
            const int cb = 4 + pc * 4;
            float4 m[6]; float L[6], R[6];
            #pragma unroll
            for (int r = 0; r < 6; ++r) {
                const int a = (h0 + r) * TS + cb;
                m[r] = *(const float4*)(tile + a);
                L[r] = tile[a - 1];
                R[r] = tile[a + 4];
            }
            #pragma unroll
            for (int orow = 0; orow < 4; ++orow) {
                floatx4 acc = {bs, bs, bs, bs};
                #pragma unroll
                for (int r = 0; r < 3; ++r) {
                    const int rr = orow + r;
                    const float wl = wgt[r * 3 + 0], wc = wgt[r * 3 + 1],
                                wr = wgt[r * 3 + 2];
                    acc.x += wl * L[rr]   + wc * m[rr].x + wr * m[rr].y;
                    acc.y += wl * m[rr].x + wc * m[rr].y + wr * m[rr].z;
                    acc.z += wl * m[rr].y + wc * m[rr].z + wr * m[rr].w;
                    acc.w += wl * m[rr].z + wc * m[rr].w + wr * R[rr];
                }
                __builtin_nontemporal_store(
                    acc, (floatx4*)(oplane + (r0 + h0 + orow) * 96 + (cb - 4)));
            }
        }
    }
}

extern "C" void kernel_launch(void* const* d_in, const int* in_sizes, int n_in,
                              void* d_out, int out_size, void* d_ws, size_t ws_size,
                              hipStream_t stream) {
    const float* x    = (const float*)d_in[0];
    const float* w_k  = (const float*)d_in[1];
    const float* b_k  = (const float*)d_in[2];
    const float* w1   = (const float*)d_in[3];
    const float* b1   = (const float*)d_in[4];
    const float* bn_g = (const float*)d_in[5];
    const float* bn_b = (const float*)d_in[6];
    const float* bn_m = (const float*)d_in[7];
    const float* bn_v = (const float*)d_in[8];
    const float* w2   = (const float*)d_in[9];
    const float* b2   = (const float*)d_in[10];
    float* out = (float*)d_out;

    float* pooled = (float*)d_ws;                 // B*C*9 floats
    float* weight = pooled + BB * CC * 9;         // B*C*9 floats
    float* bias   = weight + BB * CC * 9;         // B*C   floats

    // Cooperative grid sizing (cached): CUs * max co-resident blocks.
    static int gridSize = 0;
    if (gridSize == 0) {
        int dev = 0;
        (void)hipGetDevice(&dev);
        int cus = 256;
        (void)hipDeviceGetAttribute(&cus, hipDeviceAttributeMultiprocessorCount, dev);
        int occ = 0;
        (void)hipOccupancyMaxActiveBlocksPerMultiprocessor(&occ, fused_kernel, 256, 0);
        if (occ < 1) occ = 1;
        long g = (long)cus * occ;
        if (g > BB * CC * 2) g = BB * CC * 2;
        if (g < 1) g = 1;
        gridSize = (int)g;
    }

    void* args[] = {(void*)&x,    (void*)&w_k,  (void*)&b_k,  (void*)&w1,
                    (void*)&b1,   (void*)&bn_g, (void*)&bn_b, (void*)&bn_m,
                    (void*)&bn_v, (void*)&w2,   (void*)&b2,   (void*)&pooled,
                    (void*)&weight, (void*)&bias, (void*)&out};

    hipError_t err = hipLaunchCooperativeKernel(fused_kernel, dim3(gridSize),
                                                dim3(256), args, 0, stream);
    if (err != hipSuccess) {
        // Fallback: verified 3-kernel pipeline.
        pool_kernel<<<BB * CC, 256, 0, stream>>>(x, pooled);
        proj_kernel<<<BB * 10, 256, 0, stream>>>(pooled, w1, b1, bn_g, bn_b, bn_m,
                                                 bn_v, w2, b2, w_k, b_k, weight, bias);
        dwconv_kernel<<<BB * CC * 2, 256, 0, stream>>>(x, weight, bias, out);
    }
}

// Round 4
// 312.167 us; speedup vs baseline: 1.4705x; 1.4705x over previous
//
#include <hip/hip_runtime.h>
#include <math.h>

#define BB 16
#define CC 256
#define HH 96
#define WW 96

typedef float floatx4 __attribute__((ext_vector_type(4)));  // native vec for nontemporal store

// ---------------- Kernel 1: 32x32 block-average pool -> pooled (B,C,3,3) ----
// All 9 loads issued up front (9x memory parallelism), one sync total.
__global__ __launch_bounds__(256) void pool_kernel(const float* __restrict__ x,
                                                   float* __restrict__ pooled) {
    const int bc = blockIdx.x;                       // 0 .. B*C-1
    const float4* p4 = (const float4*)(x + (size_t)bc * (HH * WW));
    const int tid  = threadIdx.x;
    const int lane = tid & 63;
    const int wv   = tid >> 6;
    const int r_in = tid >> 3;   // 0..31  row inside a 32x32 block
    const int c4   = tid & 7;    // 0..7   float4 inside the 32-wide block
    __shared__ float red[9][4];

    float s[9];
    #pragma unroll
    for (int bi = 0; bi < 3; ++bi)
        #pragma unroll
        for (int bj = 0; bj < 3; ++bj) {
            float4 v = p4[(bi * 32 + r_in) * 24 + bj * 8 + c4];
            s[bi * 3 + bj] = v.x + v.y + v.z + v.w;
        }

    #pragma unroll
    for (int k = 0; k < 9; ++k) {
        float t = s[k];
        #pragma unroll
        for (int off = 32; off; off >>= 1) t += __shfl_down(t, off, 64);
        if (lane == 0) red[k][wv] = t;
    }
    __syncthreads();
    if (tid < 9)
        pooled[bc * 9 + tid] =
            (red[tid][0] + red[tid][1] + red[tid][2] + red[tid][3]) * (1.0f / 1024.0f);
}

// ---------------- Kernel 2: MLP + softmax(G) + mix -> weight (B,C,9), bias (B,C)
__global__ __launch_bounds__(256) void proj_kernel(
    const float* __restrict__ pooled,
    const float* __restrict__ w1, const float* __restrict__ b1,
    const float* __restrict__ bn_g, const float* __restrict__ bn_b,
    const float* __restrict__ bn_m, const float* __restrict__ bn_v,
    const float* __restrict__ w2, const float* __restrict__ b2,
    const float* __restrict__ w_k, const float* __restrict__ b_k,
    float* __restrict__ weight, float* __restrict__ bias) {
    const int b = blockIdx.x / 10;
    const int p = blockIdx.x % 10;   // 0..8 = pooled pixel, 9 = global mean
    const int tid = threadIdx.x;     // == channel c in the epilogue

    __shared__ __align__(16) float t[CC];
    __shared__ __align__(16) float hbuf[64];
    __shared__ float hpart[256];

    if (p < 9) {
        t[tid] = pooled[(b * CC + tid) * 9 + p];
    } else {
        float s = 0.f;
        #pragma unroll
        for (int q = 0; q < 9; ++q) s += pooled[(b * CC + tid) * 9 + q];
        t[tid] = s * (1.0f / 9.0f);
    }
    __syncthreads();

    // h = w1 @ t  (64 outputs, 4 partial-threads each), float4 dots
    const int o = tid & 63, part = tid >> 6;
    {
        const float4* w1r = (const float4*)(w1 + o * CC + part * 64);
        const float4* tp  = (const float4*)(t + part * 64);
        float acc = 0.f;
        #pragma unroll
        for (int k = 0; k < 16; ++k) {
            float4 a = w1r[k], v = tp[k];
            acc += a.x * v.x + a.y * v.y + a.z * v.z + a.w * v.w;
        }
        hpart[tid] = acc;
    }
    __syncthreads();
    if (tid < 64) {
        float hsum = hpart[tid] + hpart[tid + 64] + hpart[tid + 128] +
                     hpart[tid + 192] + b1[tid];
        float hn = (hsum - bn_m[tid]) * (bn_g[tid] * rsqrtf(bn_v[tid] + 1e-5f)) + bn_b[tid];
        hbuf[tid] = 0.5f * hn * (1.0f + erff(hn * 0.70710678118654752f));
    }
    __syncthreads();

    float vals[4];
    #pragma unroll
    for (int q = 0; q < 4; ++q) {
        const int j = q * 256 + tid;
        const float4* w2r = (const float4*)(w2 + j * 64);
        const float4* hb  = (const float4*)hbuf;
        float a = b2[j];
        #pragma unroll
        for (int k = 0; k < 16; ++k) {
            float4 wv = w2r[k], hv = hb[k];
            a += wv.x * hv.x + wv.y * hv.y + wv.z * hv.z + wv.w * hv.w;
        }
        vals[q] = a;
    }
    float m = fmaxf(fmaxf(vals[0], vals[1]), fmaxf(vals[2], vals[3]));
    float e[4], sum = 0.f;
    #pragma unroll
    for (int q = 0; q < 4; ++q) { e[q] = expf(vals[q] - m); sum += e[q]; }
    const float rinv = 1.0f / sum;

    if (p < 9) {
        float ws = 0.f;
        #pragma unroll
        for (int q = 0; q < 4; ++q)
            ws += (e[q] * rinv) * w_k[(q * CC + tid) * 9 + p];
        weight[(b * CC + tid) * 9 + p] = ws;
    } else {
        float bs = 0.f;
        #pragma unroll
        for (int q = 0; q < 4; ++q)
            bs += (e[q] * rinv) * b_k[q * CC + tid];
        bias[b * CC + tid] = bs;
    }
}

// ---------------- Kernel 3: dynamic depthwise 3x3 conv (SAME) + bias ---------
// LDS-FREE: x is L2/L3-hot after the pool pass (FETCH counter in R3 proved the
// conv-phase re-read never touches HBM). Each thread computes one 4x4 patch,
// reading its 6-row stencil neighborhood directly from global: per row one
// 16B-aligned float4 + 2 edge scalars — coalesced across lanes, served by
// L1/L2. No LDS, no barrier, no staging pass, no bank conflicts (9.0M conflict
// cycles in the R3 profile came from the old tile's stride-16B column reads).
// Block = 576 threads (9 waves) = one (b,c) plane, one patch per thread.
__global__ __launch_bounds__(576) void dwconv_kernel(
    const float* __restrict__ x, const float* __restrict__ weight,
    const float* __restrict__ bias, float* __restrict__ out) {
    const int bc = blockIdx.x;
    const float* plane = x + (size_t)bc * (HH * WW);
    float* oplane = out + (size_t)bc * (HH * WW);
    const int tid = threadIdx.x;     // 0..575
    const int pr  = tid / 24;        // patch row 0..23
    const int pc  = tid - pr * 24;   // patch col 0..23
    const int h0  = pr * 4;          // first output row
    const int c0  = pc * 4;          // first output col (16B aligned)

    float wgt[9];
    #pragma unroll
    for (int k = 0; k < 9; ++k) wgt[k] = weight[bc * 9 + k];
    const float bs = bias[bc];

    // input rows h0-1 .. h0+4
    float4 m[6]; float L[6], R[6];
    #pragma unroll
    for (int r = 0; r < 6; ++r) {
        const int gr = h0 + r - 1;
        if (gr >= 0 && gr < HH) {
            const float* row = plane + gr * WW + c0;
            m[r] = *(const float4*)row;
            L[r] = (pc > 0)  ? row[-1] : 0.f;
            R[r] = (pc < 23) ? row[4]  : 0.f;
        } else {
            m[r] = make_float4(0.f, 0.f, 0.f, 0.f);
            L[r] = 0.f;
            R[r] = 0.f;
        }
    }

    #pragma unroll
    for (int orow = 0; orow < 4; ++orow) {
        floatx4 acc = {bs, bs, bs, bs};
        #pragma unroll
        for (int r = 0; r < 3; ++r) {
            const int rr = orow + r;
            const float wl = wgt[r * 3 + 0], wc = wgt[r * 3 + 1],
                        wr = wgt[r * 3 + 2];
            acc.x += wl * L[rr]   + wc * m[rr].x + wr * m[rr].y;
            acc.y += wl * m[rr].x + wc * m[rr].y + wr * m[rr].z;
            acc.z += wl * m[rr].y + wc * m[rr].z + wr * m[rr].w;
            acc.w += wl * m[rr].z + wc * m[rr].w + wr * R[rr];
        }
        __builtin_nontemporal_store(
            acc, (floatx4*)(oplane + (h0 + orow) * WW + c0));
    }
}

extern "C" void kernel_launch(void* const* d_in, const int* in_sizes, int n_in,
                              void* d_out, int out_size, void* d_ws, size_t ws_size,
                              hipStream_t stream) {
    const float* x    = (const float*)d_in[0];
    const float* w_k  = (const float*)d_in[1];
    const float* b_k  = (const float*)d_in[2];
    const float* w1   = (const float*)d_in[3];
    const float* b1   = (const float*)d_in[4];
    const float* bn_g = (const float*)d_in[5];
    const float* bn_b = (const float*)d_in[6];
    const float* bn_m = (const float*)d_in[7];
    const float* bn_v = (const float*)d_in[8];
    const float* w2   = (const float*)d_in[9];
    const float* b2   = (const float*)d_in[10];
    float* out = (float*)d_out;

    float* pooled = (float*)d_ws;                 // B*C*9 floats
    float* weight = pooled + BB * CC * 9;         // B*C*9 floats
    float* bias   = weight + BB * CC * 9;         // B*C   floats

    pool_kernel<<<BB * CC, 256, 0, stream>>>(x, pooled);
    proj_kernel<<<BB * 10, 256, 0, stream>>>(pooled, w1, b1, bn_g, bn_b, bn_m,
                                             bn_v, w2, b2, w_k, b_k, weight, bias);
    dwconv_kernel<<<BB * CC, 576, 0, stream>>>(x, weight, bias, out);
}